// Round 11
// baseline (130.455 us; speedup 1.0000x reference)
//
#include <hip/hip_runtime.h>

// Int8 fake-quant linear (exact integer accumulation):
//   sx = max|x|/128; qx = clamp(rint(x/sx),-128,127)
//   sw = max|w|/127; qw = clamp(rint(w/sw),-127,127)
//   out = mul * (sx*sw*(qx @ qw^T) + bias)
//
// qx/qw stored PERMUTED in workspace, in LDS chunk-plane order (256-row blocks):
//   v4i index = ((blk*32 + kt)*4 + c)*256 + r
// -> GEMM staging is a linear contiguous copy (global_load_lds, lane-linear dest)
// -> fragment reads are 32-lane-contiguous (verified: 0 bank conflicts R3/R5)

typedef int v4i  __attribute__((ext_vector_type(4)));
typedef int v16i __attribute__((ext_vector_type(16)));

#define MDIM 4096
#define NDIM 8192
#define KDIM 2048
#define NT   (KDIM / 64)   // 32 K-tiles of BK=64 int8

typedef __attribute__((address_space(1))) void* gas_ptr;   // global
typedef __attribute__((address_space(3))) void* las_ptr;   // LDS

#define XBLK 1024   // blocks for x; w gets 2048 (total 3072)

// ---------------- absmax: per-block partial maxima (plain stores) ----------------
__global__ __launch_bounds__(256) void absmax2(const float4* __restrict__ x,
                                               const float4* __restrict__ w,
                                               float* __restrict__ partial) {
    const int tid = threadIdx.x;
    const bool isx = blockIdx.x < XBLK;
    float m0 = 0.0f, m1 = 0.0f;
    if (isx) {
        const size_t base = (size_t)blockIdx.x * 256 + tid;       // stride 262144
#pragma unroll
        for (int j = 0; j < 8; j += 2) {
            float4 v0 = x[base + (size_t)j * 262144];
            float4 v1 = x[base + (size_t)(j + 1) * 262144];
            m0 = fmaxf(m0, fmaxf(fmaxf(fabsf(v0.x), fabsf(v0.y)),
                                 fmaxf(fabsf(v0.z), fabsf(v0.w))));
            m1 = fmaxf(m1, fmaxf(fmaxf(fabsf(v1.x), fabsf(v1.y)),
                                 fmaxf(fabsf(v1.z), fabsf(v1.w))));
        }
    } else {
        const size_t base = (size_t)(blockIdx.x - XBLK) * 256 + tid;  // stride 524288
#pragma unroll
        for (int j = 0; j < 8; j += 2) {
            float4 v0 = w[base + (size_t)j * 524288];
            float4 v1 = w[base + (size_t)(j + 1) * 524288];
            m0 = fmaxf(m0, fmaxf(fmaxf(fabsf(v0.x), fabsf(v0.y)),
                                 fmaxf(fabsf(v0.z), fabsf(v0.w))));
            m1 = fmaxf(m1, fmaxf(fmaxf(fabsf(v1.x), fabsf(v1.y)),
                                 fmaxf(fabsf(v1.z), fabsf(v1.w))));
        }
    }
    float m = fmaxf(m0, m1);
#pragma unroll
    for (int off = 32; off > 0; off >>= 1)
        m = fmaxf(m, __shfl_xor(m, off, 64));
    __shared__ float wm[4];
    if ((tid & 63) == 0) wm[tid >> 6] = m;
    __syncthreads();
    if (tid == 0)
        partial[blockIdx.x] = fmaxf(fmaxf(wm[0], wm[1]), fmaxf(wm[2], wm[3]));
}

// ---------------- quantize: reduce partials, then permuted int8 write ----------
__global__ __launch_bounds__(256) void quant2(const float4* __restrict__ x,
                                              v4i* __restrict__ qxp,
                                              const float4* __restrict__ w,
                                              v4i* __restrict__ qwp,
                                              const float* __restrict__ partial,
                                              unsigned* __restrict__ scales) {
    const int tid = threadIdx.x;
    float gx = 0.0f, gw = 0.0f;
#pragma unroll
    for (int j = 0; j < 4; ++j) gx = fmaxf(gx, partial[tid + j * 256]);
#pragma unroll
    for (int j = 0; j < 8; ++j) gw = fmaxf(gw, partial[XBLK + tid + j * 256]);
#pragma unroll
    for (int off = 32; off > 0; off >>= 1) {
        gx = fmaxf(gx, __shfl_xor(gx, off, 64));
        gw = fmaxf(gw, __shfl_xor(gw, off, 64));
    }
    __shared__ float smx[4], smw[4];
    if ((tid & 63) == 0) { smx[tid >> 6] = gx; smw[tid >> 6] = gw; }
    __syncthreads();
    const float fmx = fmaxf(fmaxf(smx[0], smx[1]), fmaxf(smx[2], smx[3]));
    const float fmw = fmaxf(fmaxf(smw[0], smw[1]), fmaxf(smw[2], smw[3]));
    if (blockIdx.x == 0 && tid == 0) {
        scales[0] = __float_as_uint(fmx);
        scales[1] = __float_as_uint(fmw);
    }
    const float sxs = fmx / 128.0f;   // IEEE, matches reference scale
    const float sws = fmw / 127.0f;

    const bool isx = blockIdx.x < XBLK;
    const float4* in = isx ? x : w;
    v4i* outp = isx ? qxp : qwp;
    const int total = isx ? (MDIM * KDIM / 16) : (NDIM * KDIM / 16);
    const int nb = isx ? XBLK : (3072 - XBLK);
    const int b  = isx ? blockIdx.x : (blockIdx.x - XBLK);
    const float s  = isx ? sxs : sws;
    const float lo = isx ? -128.0f : -127.0f;
    for (int idx = b * 256 + tid; idx < total; idx += nb * 256) {
        const int c   = idx & 3;
        const int r   = (idx >> 2) & 255;
        const int kt  = (idx >> 10) & 31;
        const int blk = idx >> 15;
        const float4* src = in + (size_t)(blk * 256 + r) * (KDIM / 4) + kt * 16 + c * 4;
        int q[4];
#pragma unroll
        for (int j = 0; j < 4; ++j) {
            float4 v = src[j];
            int b0 = (int)fminf(fmaxf(rintf(v.x / s), lo), 127.0f);
            int b1 = (int)fminf(fmaxf(rintf(v.y / s), lo), 127.0f);
            int b2 = (int)fminf(fmaxf(rintf(v.z / s), lo), 127.0f);
            int b3 = (int)fminf(fmaxf(rintf(v.w / s), lo), 127.0f);
            q[j] = (b0 & 255) | ((b1 & 255) << 8) | ((b2 & 255) << 16) | (b3 << 24);
        }
        v4i qq; qq[0] = q[0]; qq[1] = q[1]; qq[2] = q[2]; qq[3] = q[3];
        outp[((size_t)(blk * 32 + kt) * 4 + c) * 256 + r] = qq;
    }
}

// ---------------- int8 MFMA GEMM, m201-style 8-phase schedule ----------------
// 256x256 tile, ring-4 LDS (128 KiB), 8 waves (2M x 4N); wave output 128x64 =
// 4x2 mfma_i32_32x32x32_i8. Per K-tile: 4 quadrant-phases, each
// {ds_reads (6/2/4/0); 1 global_load_lds; s_barrier; lgkmcnt(0);
//  sched_barrier; setprio(1); 4 MFMA; setprio(0); s_barrier}.
// Fragment reuse across phases: A-mt01 live ph1-2, B-nt1 ph2-3, B-nt0 ph1-4,
// A-mt23 ph3-4. Counted vmcnt ONLY at phase-4/8 boundaries (8, taper 4->0).
__global__ __launch_bounds__(512, 2) void gemm_i8(
    const signed char* __restrict__ qxp, const signed char* __restrict__ qwp,
    const float* __restrict__ bias, const float* __restrict__ mulv,
    const unsigned* __restrict__ scales, float* __restrict__ out) {
    __shared__ signed char ldsA[4][16384];
    __shared__ signed char ldsB[4][16384];

    const int t    = threadIdx.x;
    const int lane = t & 63;
    const int ln   = lane & 31;
    const int hi   = lane >> 5;
    const int w    = t >> 6;      // 0..7
    const int wr   = w >> 2;      // 0..1  (M half)
    const int wc   = w & 3;       // 0..3  (N quarter)

    // XCD-aware swizzle: 512 workgroups, 512 % 8 == 0 -> simple bijection.
    const int orig = blockIdx.x;
    const int wg   = ((orig & 7) << 6) | (orig >> 3);
    const int bm   = wg >> 5;     // 0..15
    const int bn   = wg & 31;     // 0..31

    const signed char* srcA = qxp + (size_t)bm * (32 * 16384);
    const signed char* srcB = qwp + (size_t)bn * (32 * 16384);
    signed char* dA = &ldsA[0][0] + t * 16;   // wave-uniform base + lane*16
    signed char* dB = &ldsB[0][0] + t * 16;

    // one staging load (1/4 of a tile); parts: 0=A-lo,1=A-hi,2=B-lo,3=B-hi
    auto stage1 = [&](int kt, int part) {
        if (kt >= NT) return;
        const int buf = kt & 3;
        if (part == 0)
            __builtin_amdgcn_global_load_lds((gas_ptr)(srcA + kt * 16384 + t * 16),
                                             (las_ptr)(dA + buf * 16384), 16, 0, 0);
        else if (part == 1)
            __builtin_amdgcn_global_load_lds((gas_ptr)(srcA + kt * 16384 + 8192 + t * 16),
                                             (las_ptr)(dA + buf * 16384 + 8192), 16, 0, 0);
        else if (part == 2)
            __builtin_amdgcn_global_load_lds((gas_ptr)(srcB + kt * 16384 + t * 16),
                                             (las_ptr)(dB + buf * 16384), 16, 0, 0);
        else
            __builtin_amdgcn_global_load_lds((gas_ptr)(srcB + kt * 16384 + 8192 + t * 16),
                                             (las_ptr)(dB + buf * 16384 + 8192), 16, 0, 0);
    };

    auto waitv = [&](int n) {
        if (n == 8)      asm volatile("s_waitcnt vmcnt(8)" ::: "memory");
        else if (n == 4) asm volatile("s_waitcnt vmcnt(4)" ::: "memory");
        else if (n == 0) asm volatile("s_waitcnt vmcnt(0)" ::: "memory");
    };

    // fragment offsets (chunk-plane: plane = 2*ks+hi, 32-lane contiguous)
    const int aOff = (wr * 128 + ln) * 16;   // + mt*512 + plane*4096
    const int bOff = (wc * 64  + ln) * 16;   // + nt*512 + plane*4096

#define RD(base, plane, off) (*(const v4i*)((base) + (plane) * 4096 + (off)))
#define MF(A, B, C) __builtin_amdgcn_mfma_i32_32x32x32_i8(A, B, C, 0, 0, 0)
#define LGKM0 do { asm volatile("s_waitcnt lgkmcnt(0)" ::: "memory"); \
                   __builtin_amdgcn_sched_barrier(0); } while (0)

    v16i acc[4][2];
#pragma unroll
    for (int mt = 0; mt < 4; ++mt)
#pragma unroll
        for (int nt = 0; nt < 2; ++nt)
#pragma unroll
            for (int r = 0; r < 16; ++r) acc[mt][nt][r] = 0;

    // 4 quadrant-phases of one K-tile (m201 shape). wn = vmcnt at tile end (-1 none).
    auto tile4 = [&](int buf, int sT, int wn) {
        const signed char* Ab = &ldsA[buf][0];
        const signed char* Bb = &ldsB[buf][0];
        v4i aA0, aA1, aA2, aA3;   // A mt0/mt1: ks0 pair then ks1 pair
        v4i aB0, aB1, aB2, aB3;   // A mt2/mt3
        v4i b00, b01, b10, b11;   // B nt0 (ks0,ks1), B nt1 (ks0,ks1)

        // ---- phase 1: quadrant (mt01, nt0) ----
        aA0 = RD(Ab, hi, aOff);          aA1 = RD(Ab, hi, aOff + 512);
        aA2 = RD(Ab, 2 + hi, aOff);      aA3 = RD(Ab, 2 + hi, aOff + 512);
        b00 = RD(Bb, hi, bOff);          b01 = RD(Bb, 2 + hi, bOff);
        stage1(sT, 0);
        __builtin_amdgcn_s_barrier();
        LGKM0;
        __builtin_amdgcn_s_setprio(1);
        acc[0][0] = MF(aA0, b00, acc[0][0]);
        acc[0][0] = MF(aA2, b01, acc[0][0]);
        acc[1][0] = MF(aA1, b00, acc[1][0]);
        acc[1][0] = MF(aA3, b01, acc[1][0]);
        __builtin_amdgcn_s_setprio(0);
        __builtin_amdgcn_s_barrier();

        // ---- phase 2: quadrant (mt01, nt1) ----
        b10 = RD(Bb, hi, bOff + 512);    b11 = RD(Bb, 2 + hi, bOff + 512);
        stage1(sT, 1);
        __builtin_amdgcn_s_barrier();
        LGKM0;
        __builtin_amdgcn_s_setprio(1);
        acc[0][1] = MF(aA0, b10, acc[0][1]);
        acc[0][1] = MF(aA2, b11, acc[0][1]);
        acc[1][1] = MF(aA1, b10, acc[1][1]);
        acc[1][1] = MF(aA3, b11, acc[1][1]);
        __builtin_amdgcn_s_setprio(0);
        __builtin_amdgcn_s_barrier();

        // ---- phase 3: quadrant (mt23, nt1) ----
        aB0 = RD(Ab, hi, aOff + 1024);   aB1 = RD(Ab, hi, aOff + 1536);
        aB2 = RD(Ab, 2 + hi, aOff + 1024); aB3 = RD(Ab, 2 + hi, aOff + 1536);
        stage1(sT, 2);
        __builtin_amdgcn_s_barrier();
        LGKM0;
        __builtin_amdgcn_s_setprio(1);
        acc[2][1] = MF(aB0, b10, acc[2][1]);
        acc[2][1] = MF(aB2, b11, acc[2][1]);
        acc[3][1] = MF(aB1, b10, acc[3][1]);
        acc[3][1] = MF(aB3, b11, acc[3][1]);
        __builtin_amdgcn_s_setprio(0);
        __builtin_amdgcn_s_barrier();

        // ---- phase 4: quadrant (mt23, nt0); no reads; tile-boundary vmcnt ----
        stage1(sT, 3);
        __builtin_amdgcn_s_barrier();
        __builtin_amdgcn_s_setprio(1);
        acc[2][0] = MF(aB0, b00, acc[2][0]);
        acc[2][0] = MF(aB2, b01, acc[2][0]);
        acc[3][0] = MF(aB1, b00, acc[3][0]);
        acc[3][0] = MF(aB3, b01, acc[3][0]);
        __builtin_amdgcn_s_setprio(0);
        if (wn >= 0) waitv(wn);
        __builtin_amdgcn_s_barrier();
    };

    // ---- prologue: stage tiles 0,1,2 (12 loads); tile 0 resident ----
#pragma unroll
    for (int kt = 0; kt < 3; ++kt)
#pragma unroll
        for (int p = 0; p < 4; ++p) stage1(kt, p);
    asm volatile("s_waitcnt vmcnt(8)" ::: "memory");
    __builtin_amdgcn_s_barrier();

    for (int j = 0; j < 16; ++j) {
        // phases 1-4: tile 2j; stage tile 2j+3 (one load per phase)
        tile4((2 * j) & 3, 2 * j + 3, (j <= 14) ? 8 : 0);
        // phases 5-8: tile 2j+1; stage tile 2j+4
        tile4((2 * j + 1) & 3, 2 * j + 4,
              (j < 14) ? 8 : ((j == 14) ? 4 : -1));
    }

    // ---- epilogue: out = fs*acc + mul*bias ----
    // C/D layout (32x32): col = lane&31, row = (r&3) + 8*(r>>2) + 4*(lane>>5)
    const float fm = mulv[0];
    const float fs = fm * (__uint_as_float(scales[0]) / 128.0f)
                        * (__uint_as_float(scales[1]) / 127.0f);
    const int colb = bn * 256 + wc * 64 + ln;
    const int hi4  = hi * 4;
#pragma unroll
    for (int nt = 0; nt < 2; ++nt) {
        const int ocol = colb + nt * 32;
        const float bv = bias[ocol] * fm;
#pragma unroll
        for (int mt = 0; mt < 4; ++mt) {
            float* op = out + (size_t)(bm * 256 + wr * 128 + mt * 32) * NDIM + ocol;
#pragma unroll
            for (int r = 0; r < 16; ++r) {
                const int row = (r & 3) + 8 * (r >> 2) + hi4;
                op[(size_t)row * NDIM] = fs * (float)acc[mt][nt][r] + bv;
            }
        }
    }
#undef RD
#undef MF
#undef LGKM0
}

extern "C" void kernel_launch(void* const* d_in, const int* in_sizes, int n_in,
                              void* d_out, int out_size, void* d_ws, size_t ws_size,
                              hipStream_t stream) {
    const float4* x    = (const float4*)d_in[0];
    const float4* wgt  = (const float4*)d_in[1];
    const float*  bias = (const float*)d_in[2];
    const float*  mulv = (const float*)d_in[3];
    float* out = (float*)d_out;

    // workspace: scales @0 (8B), partials @256 (12KB), qxp @16640, qwp next
    unsigned* scales  = (unsigned*)d_ws;
    float*    partial = (float*)((char*)d_ws + 256);
    signed char* qxp  = (signed char*)d_ws + 256 + 16384;
    signed char* qwp  = qxp + (size_t)MDIM * KDIM;

    absmax2<<<3072, 256, 0, stream>>>(x, wgt, partial);
    quant2<<<3072, 256, 0, stream>>>(x, (v4i*)qxp, wgt, (v4i*)qwp,
                                     partial, scales);
    gemm_i8<<<512, 512, 0, stream>>>(qxp, qwp, bias, mulv, scales, out);
}

// Round 12
// 122.344 us; speedup vs baseline: 1.0663x; 1.0663x over previous
//
#include <hip/hip_runtime.h>

// Int8 fake-quant linear (exact integer accumulation):
//   sx = max|x|/128; qx = clamp(rint(x/sx),-128,127)
//   sw = max|w|/127; qw = clamp(rint(w/sw),-127,127)
//   out = mul * (sx*sw*(qx @ qw^T) + bias)
//
// qx/qw stored PERMUTED in workspace, in LDS chunk-plane order (256-row blocks):
//   v4i index = ((blk*32 + kt)*4 + c)*256 + r
// -> GEMM staging is a linear contiguous copy (global_load_lds, lane-linear dest)
// -> fragment reads are 32-lane-contiguous (verified: 0 bank conflicts R3/R5)

typedef int v4i  __attribute__((ext_vector_type(4)));
typedef int v16i __attribute__((ext_vector_type(16)));

#define MDIM 4096
#define NDIM 8192
#define KDIM 2048
#define NT   (KDIM / 64)   // 32 K-tiles of BK=64 int8

typedef __attribute__((address_space(1))) void* gas_ptr;   // global
typedef __attribute__((address_space(3))) void* las_ptr;   // LDS

#define XBLK 1024   // blocks for x; w gets 2048 (total 3072)

// ---------------- absmax: per-block partial maxima (plain stores) ----------------
__global__ __launch_bounds__(256) void absmax2(const float4* __restrict__ x,
                                               const float4* __restrict__ w,
                                               float* __restrict__ partial) {
    const int tid = threadIdx.x;
    const bool isx = blockIdx.x < XBLK;
    float m0 = 0.0f, m1 = 0.0f;
    if (isx) {
        const size_t base = (size_t)blockIdx.x * 256 + tid;       // stride 262144
#pragma unroll
        for (int j = 0; j < 8; j += 2) {
            float4 v0 = x[base + (size_t)j * 262144];
            float4 v1 = x[base + (size_t)(j + 1) * 262144];
            m0 = fmaxf(m0, fmaxf(fmaxf(fabsf(v0.x), fabsf(v0.y)),
                                 fmaxf(fabsf(v0.z), fabsf(v0.w))));
            m1 = fmaxf(m1, fmaxf(fmaxf(fabsf(v1.x), fabsf(v1.y)),
                                 fmaxf(fabsf(v1.z), fabsf(v1.w))));
        }
    } else {
        const size_t base = (size_t)(blockIdx.x - XBLK) * 256 + tid;  // stride 524288
#pragma unroll
        for (int j = 0; j < 8; j += 2) {
            float4 v0 = w[base + (size_t)j * 524288];
            float4 v1 = w[base + (size_t)(j + 1) * 524288];
            m0 = fmaxf(m0, fmaxf(fmaxf(fabsf(v0.x), fabsf(v0.y)),
                                 fmaxf(fabsf(v0.z), fabsf(v0.w))));
            m1 = fmaxf(m1, fmaxf(fmaxf(fabsf(v1.x), fabsf(v1.y)),
                                 fmaxf(fabsf(v1.z), fabsf(v1.w))));
        }
    }
    float m = fmaxf(m0, m1);
#pragma unroll
    for (int off = 32; off > 0; off >>= 1)
        m = fmaxf(m, __shfl_xor(m, off, 64));
    __shared__ float wm[4];
    if ((tid & 63) == 0) wm[tid >> 6] = m;
    __syncthreads();
    if (tid == 0)
        partial[blockIdx.x] = fmaxf(fmaxf(wm[0], wm[1]), fmaxf(wm[2], wm[3]));
}

// ---------------- quantize: reduce partials, then permuted int8 write ----------
__global__ __launch_bounds__(256) void quant2(const float4* __restrict__ x,
                                              v4i* __restrict__ qxp,
                                              const float4* __restrict__ w,
                                              v4i* __restrict__ qwp,
                                              const float* __restrict__ partial,
                                              unsigned* __restrict__ scales) {
    const int tid = threadIdx.x;
    float gx = 0.0f, gw = 0.0f;
#pragma unroll
    for (int j = 0; j < 4; ++j) gx = fmaxf(gx, partial[tid + j * 256]);
#pragma unroll
    for (int j = 0; j < 8; ++j) gw = fmaxf(gw, partial[XBLK + tid + j * 256]);
#pragma unroll
    for (int off = 32; off > 0; off >>= 1) {
        gx = fmaxf(gx, __shfl_xor(gx, off, 64));
        gw = fmaxf(gw, __shfl_xor(gw, off, 64));
    }
    __shared__ float smx[4], smw[4];
    if ((tid & 63) == 0) { smx[tid >> 6] = gx; smw[tid >> 6] = gw; }
    __syncthreads();
    const float fmx = fmaxf(fmaxf(smx[0], smx[1]), fmaxf(smx[2], smx[3]));
    const float fmw = fmaxf(fmaxf(smw[0], smw[1]), fmaxf(smw[2], smw[3]));
    if (blockIdx.x == 0 && tid == 0) {
        scales[0] = __float_as_uint(fmx);
        scales[1] = __float_as_uint(fmw);
    }
    const float sxs = fmx / 128.0f;   // IEEE, matches reference scale
    const float sws = fmw / 127.0f;

    const bool isx = blockIdx.x < XBLK;
    const float4* in = isx ? x : w;
    v4i* outp = isx ? qxp : qwp;
    const int total = isx ? (MDIM * KDIM / 16) : (NDIM * KDIM / 16);
    const int nb = isx ? XBLK : (3072 - XBLK);
    const int b  = isx ? blockIdx.x : (blockIdx.x - XBLK);
    const float s  = isx ? sxs : sws;
    const float lo = isx ? -128.0f : -127.0f;
    for (int idx = b * 256 + tid; idx < total; idx += nb * 256) {
        const int c   = idx & 3;
        const int r   = (idx >> 2) & 255;
        const int kt  = (idx >> 10) & 31;
        const int blk = idx >> 15;
        const float4* src = in + (size_t)(blk * 256 + r) * (KDIM / 4) + kt * 16 + c * 4;
        int q[4];
#pragma unroll
        for (int j = 0; j < 4; ++j) {
            float4 v = src[j];
            int b0 = (int)fminf(fmaxf(rintf(v.x / s), lo), 127.0f);
            int b1 = (int)fminf(fmaxf(rintf(v.y / s), lo), 127.0f);
            int b2 = (int)fminf(fmaxf(rintf(v.z / s), lo), 127.0f);
            int b3 = (int)fminf(fmaxf(rintf(v.w / s), lo), 127.0f);
            q[j] = (b0 & 255) | ((b1 & 255) << 8) | ((b2 & 255) << 16) | (b3 << 24);
        }
        v4i qq; qq[0] = q[0]; qq[1] = q[1]; qq[2] = q[2]; qq[3] = q[3];
        outp[((size_t)(blk * 32 + kt) * 4 + c) * 256 + r] = qq;
    }
}

// ---------------- int8 MFMA GEMM (R5 schedule + 8x8 supertile L2 swizzle) ----
// 256x256 tile, 4-deep ring, 8 waves (2M x 4N); wave output 128x64 =
// 4x2 mfma_i32_32x32x32_i8. Per tile (proven R5 phase): {12 ds_read_b128;
// stage tile kt+3; s_barrier; setprio(1); 16 MFMA; setprio(0); s_barrier};
// counted vmcnt(4) once per 2 tiles, never drained early.
// NEW: each XCD owns an 8x8 supertile of (bm,bn) -> per-XCD working set
// 4MB A + 4MB B (was 17MB); nontemporal C-stores keep L3 for input panels.
__global__ __launch_bounds__(512, 2) void gemm_i8(
    const signed char* __restrict__ qxp, const signed char* __restrict__ qwp,
    const float* __restrict__ bias, const float* __restrict__ mulv,
    const unsigned* __restrict__ scales, float* __restrict__ out) {
    __shared__ signed char ldsA[4][16384];
    __shared__ signed char ldsB[4][16384];

    const int t    = threadIdx.x;
    const int lane = t & 63;
    const int ln   = lane & 31;
    const int hi   = lane >> 5;
    const int w    = t >> 6;      // 0..7
    const int wr   = w >> 2;      // 0..1  (M half)
    const int wc   = w & 3;       // 0..3  (N quarter)

    // 8x8 supertile per XCD: xcd = orig&7 owns bm-block (xcd&1), bn-block (xcd>>1).
    // Bijective over the 16x32 (bm,bn) grid; per-XCD working set 8 A + 8 B panels.
    const int orig = blockIdx.x;
    const int xcd  = orig & 7;
    const int idx  = orig >> 3;            // 0..63 within the supertile
    const int bm   = (xcd & 1) * 8 + (idx >> 3);   // 0..15
    const int bn   = (xcd >> 1) * 8 + (idx & 7);   // 0..31

    const signed char* srcA = qxp + (size_t)bm * (32 * 16384);
    const signed char* srcB = qwp + (size_t)bn * (32 * 16384);
    signed char* dA = &ldsA[0][0] + t * 16;   // wave-uniform base + lane*16
    signed char* dB = &ldsB[0][0] + t * 16;

    auto stage = [&](int buf, int kt) {
        const signed char* sa = srcA + kt * 16384 + t * 16;
        const signed char* sb = srcB + kt * 16384 + t * 16;
        __builtin_amdgcn_global_load_lds((gas_ptr)sa,          (las_ptr)(dA + buf * 16384),        16, 0, 0);
        __builtin_amdgcn_global_load_lds((gas_ptr)(sa + 8192), (las_ptr)(dA + buf * 16384 + 8192), 16, 0, 0);
        __builtin_amdgcn_global_load_lds((gas_ptr)sb,          (las_ptr)(dB + buf * 16384),        16, 0, 0);
        __builtin_amdgcn_global_load_lds((gas_ptr)(sb + 8192), (las_ptr)(dB + buf * 16384 + 8192), 16, 0, 0);
    };

    // ---- fragment offsets (chunk-plane: plane = 2*s+hi, 32-lane contiguous) ----
    const int aOff = (wr * 128 + ln) * 16;   // + mt*512 + plane*4096
    const int bOff = (wc * 64  + ln) * 16;   // + nt*512 + plane*4096

    v16i acc[4][2];
#pragma unroll
    for (int mt = 0; mt < 4; ++mt)
#pragma unroll
        for (int nt = 0; nt < 2; ++nt)
#pragma unroll
            for (int r = 0; r < 16; ++r) acc[mt][nt][r] = 0;

    // One full-tile phase: reads -> stage -> bar -> prio1 16 MFMA prio0.
    auto phase = [&](int kt, int stageKt) {
        const int buf = kt & 3;
        const signed char* A0 = &ldsA[buf][0] + hi * 4096;        // k-step 0
        const signed char* B0 = &ldsB[buf][0] + hi * 4096;
        const signed char* A1 = &ldsA[buf][0] + (2 + hi) * 4096;  // k-step 1
        const signed char* B1 = &ldsB[buf][0] + (2 + hi) * 4096;

        v4i a0[4], a1[4], b0[2], b1[2];
#pragma unroll
        for (int mt = 0; mt < 4; ++mt) a0[mt] = *(const v4i*)(A0 + aOff + mt * 512);
#pragma unroll
        for (int nt = 0; nt < 2; ++nt) b0[nt] = *(const v4i*)(B0 + bOff + nt * 512);
#pragma unroll
        for (int mt = 0; mt < 4; ++mt) a1[mt] = *(const v4i*)(A1 + aOff + mt * 512);
#pragma unroll
        for (int nt = 0; nt < 2; ++nt) b1[nt] = *(const v4i*)(B1 + bOff + nt * 512);

        if (stageKt < NT) stage(stageKt & 3, stageKt);
        __builtin_amdgcn_s_barrier();
        __builtin_amdgcn_s_setprio(1);
#pragma unroll
        for (int mt = 0; mt < 4; ++mt)
#pragma unroll
            for (int nt = 0; nt < 2; ++nt)
                acc[mt][nt] = __builtin_amdgcn_mfma_i32_32x32x32_i8(
                    a0[mt], b0[nt], acc[mt][nt], 0, 0, 0);
#pragma unroll
        for (int mt = 0; mt < 4; ++mt)
#pragma unroll
            for (int nt = 0; nt < 2; ++nt)
                acc[mt][nt] = __builtin_amdgcn_mfma_i32_32x32x32_i8(
                    a1[mt], b1[nt], acc[mt][nt], 0, 0, 0);
        __builtin_amdgcn_s_setprio(0);
    };

    // ---- prologue: 3 tiles in flight; tiles 0,1 resident before loop ----
    stage(0, 0);
    stage(1, 1);
    stage(2, 2);
    asm volatile("s_waitcnt vmcnt(4)" ::: "memory");   // tiles 0,1 done
    __builtin_amdgcn_s_barrier();

    for (int j = 0; j < 15; ++j) {
        phase(2 * j, 2 * j + 3);
        __builtin_amdgcn_s_barrier();
        phase(2 * j + 1, 2 * j + 4);
        // tiles 2j+2, 2j+3 resident for next iter; 2j+4 stays in flight
        asm volatile("s_waitcnt vmcnt(4)" ::: "memory");
        __builtin_amdgcn_s_barrier();
    }
    phase(30, NT);                                     // no staging left
    asm volatile("s_waitcnt vmcnt(0)" ::: "memory");   // tile 31 done
    __builtin_amdgcn_s_barrier();
    phase(31, NT);

    // ---- epilogue: out = fs*acc + mul*bias (nontemporal C-stream) ----
    // C/D layout (32x32): col = lane&31, row = (r&3) + 8*(r>>2) + 4*(lane>>5)
    const float fm = mulv[0];
    const float fs = fm * (__uint_as_float(scales[0]) / 128.0f)
                        * (__uint_as_float(scales[1]) / 127.0f);
    const int colb = bn * 256 + wc * 64 + ln;
    const int hi4  = hi * 4;
#pragma unroll
    for (int nt = 0; nt < 2; ++nt) {
        const int ocol = colb + nt * 32;
        const float bv = bias[ocol] * fm;
#pragma unroll
        for (int mt = 0; mt < 4; ++mt) {
            float* op = out + (size_t)(bm * 256 + wr * 128 + mt * 32) * NDIM + ocol;
#pragma unroll
            for (int r = 0; r < 16; ++r) {
                const int row = (r & 3) + 8 * (r >> 2) + hi4;
                __builtin_nontemporal_store(fs * (float)acc[mt][nt][r] + bv,
                                            op + (size_t)row * NDIM);
            }
        }
    }
}

extern "C" void kernel_launch(void* const* d_in, const int* in_sizes, int n_in,
                              void* d_out, int out_size, void* d_ws, size_t ws_size,
                              hipStream_t stream) {
    const float4* x    = (const float4*)d_in[0];
    const float4* wgt  = (const float4*)d_in[1];
    const float*  bias = (const float*)d_in[2];
    const float*  mulv = (const float*)d_in[3];
    float* out = (float*)d_out;

    // workspace: scales @0 (8B), partials @256 (12KB), qxp @16640, qwp next
    unsigned* scales  = (unsigned*)d_ws;
    float*    partial = (float*)((char*)d_ws + 256);
    signed char* qxp  = (signed char*)d_ws + 256 + 16384;
    signed char* qwp  = qxp + (size_t)MDIM * KDIM;

    absmax2<<<3072, 256, 0, stream>>>(x, wgt, partial);
    quant2<<<3072, 256, 0, stream>>>(x, (v4i*)qxp, wgt, (v4i*)qwp,
                                     partial, scales);
    gemm_i8<<<512, 512, 0, stream>>>(qxp, qwp, bias, mulv, scales, out);
}